// Round 13
// baseline (14.877 us; speedup 1.0000x reference)
//
#include <hip/hip_runtime.h>
#include <math.h>

// SSKernelDiag: out[0,h,l] = 2*Re( sum_n C'[h,n] * A[h,n]^l )
//   A = exp(al + i*ph),  C' = (C0 + i*C1)*(A-1)/(al + i*ph)
// H=256, N=64, L=4096.
//
// Round 13: minimum-critical-path MFMA version.
//   l = 64a + b; K[a,b] = sum_n M[n,a]*G[n,b]; M = 2C'*U^a (U=A^64), G = A^b;
//   Re(K) = Gr^T Mr + (-Gi)^T Mi -> mfma_f32_16x16x32_f16. Grid=256, 4 waves.
// Changes vs R10 (9.78us):
//   - no phase-A LDS/barrier: constants computed redundantly per thread
//   - G/M stored as 4 separate f16 planes (Re/Im) -> frag reads are direct
//     ds_read_b128 into f16x8, ZERO unpack VALU
//   - fill: thread owns an n-PAIR, walks 8 rows, packs via v_cvt_pkrtz
//     (one b32 write per plane per row)
//   - XOR swizzle ((n2>>2)^(row&7) on u32 groups): fill writes stay
//     contiguous (2/bank = free), frag reads bank-spread per quarter-wave

typedef _Float16 f16x8 __attribute__((ext_vector_type(8)));
typedef float    f32x4 __attribute__((ext_vector_type(4)));

constexpr int H = 256;
constexpr int N = 64;
constexpr int L = 4096;

__global__ __launch_bounds__(256)
void sskdiag_kernel(const float* __restrict__ A_abslog,
                    const float* __restrict__ A_phase,
                    const float* __restrict__ C,
                    float* __restrict__ out)
{
    // 4 planes, [row 0..63][32 u32] = 128 B/row, 8 KB each (32 KB total)
    __shared__ __align__(16) unsigned s_Gr[64 * 32], s_Gi[64 * 32];
    __shared__ __align__(16) unsigned s_Mr[64 * 32], s_Mi[64 * 32];

    const int h   = blockIdx.x;
    const int tid = threadIdx.x;
    const int n2  = tid & 31;          // n-pair index: n = 2*n2, 2*n2+1
    const int q   = tid >> 5;          // [0,8): seed row 8q

    // coalesced loads for the pair (first thing in the kernel)
    const float2 alv = *reinterpret_cast<const float2*>(&A_abslog[h * N + 2 * n2]);
    const float2 phv = *reinterpret_cast<const float2*>(&A_phase [h * N + 2 * n2]);
    const float4 cv  = *reinterpret_cast<const float4*>(&C[(h * N + 2 * n2) * 2]);

    float Ar[2], Ai[2], Ur[2], Ui[2];
    float g_re[2], g_im[2], m_re[2], m_im[2];

    #pragma unroll
    for (int t = 0; t < 2; ++t) {
        const float al = t ? alv.y : alv.x;
        const float ph = t ? phv.y : phv.x;
        const double md = (double)ph * 0.15915494309189535;    // ph/(2*pi)
        const float phrev = (float)(md - floor(md));           // frac revolutions
        const float sp = __builtin_amdgcn_sinf(phrev);         // HW trig: revs
        const float cp = __builtin_amdgcn_cosf(phrev);
        const float ma = __expf(al);
        Ar[t] = ma * cp;  Ai[t] = ma * sp;
        const float nr = Ar[t] - 1.0f, ni = Ai[t];
        const float inv = 1.0f / (al * al + ph * ph);
        const float gr = (nr * al + ni * ph) * inv;
        const float gi = (ni * al - nr * ph) * inv;
        const float cre = t ? cv.z : cv.x;
        const float cim = t ? cv.w : cv.y;
        const float Cr = 2.0f * (cre * gr - cim * gi);         // fold the *2
        const float Ci = 2.0f * (cre * gi + cim * gr);
        // U = A^64 (angle from f64 md: exact reduction)
        const double m64 = 64.0 * md;
        const float f64a = (float)(m64 - floor(m64));
        const float mg64 = __expf(64.0f * al);
        Ur[t] = mg64 * __builtin_amdgcn_cosf(f64a);
        Ui[t] = mg64 * __builtin_amdgcn_sinf(f64a);
        // G seed: A^(8q)
        const float b0 = (float)(8 * q);
        float tg = phrev * b0;  tg -= floorf(tg);
        const float gm = __expf(al * b0);
        g_re[t] = gm * __builtin_amdgcn_cosf(tg);
        g_im[t] = gm * __builtin_amdgcn_sinf(tg);
        // M seed: 2C' * A^(512q)  (row a = 8q, exponent 64a)
        const float e0 = (float)(512 * q);
        float tm = phrev * e0;  tm -= floorf(tm);
        const float um = __expf(al * e0);
        const float ur = um * __builtin_amdgcn_cosf(tm);
        const float ui = um * __builtin_amdgcn_sinf(tm);
        m_re[t] = Cr * ur - Ci * ui;
        m_im[t] = Cr * ui + Ci * ur;
    }

    // ---- walk 8 rows; one packed b32 write per plane per row ----
    #pragma unroll
    for (int k = 0; k < 8; ++k) {
        const int row  = 8 * q + k;
        const int scol = (((n2 >> 2) ^ (row & 7)) << 2) | (n2 & 3);
        const int idx  = row * 32 + scol;
        s_Gr[idx] = __builtin_bit_cast(unsigned,
                        __builtin_amdgcn_cvt_pkrtz(g_re[0], g_re[1]));
        s_Gi[idx] = __builtin_bit_cast(unsigned,
                        __builtin_amdgcn_cvt_pkrtz(-g_im[0], -g_im[1]));  // -Gi
        s_Mr[idx] = __builtin_bit_cast(unsigned,
                        __builtin_amdgcn_cvt_pkrtz(m_re[0], m_re[1]));
        s_Mi[idx] = __builtin_bit_cast(unsigned,
                        __builtin_amdgcn_cvt_pkrtz(m_im[0], m_im[1]));
        #pragma unroll
        for (int t = 0; t < 2; ++t) {
            const float ng = g_re[t] * Ar[t] - g_im[t] * Ai[t];   // g *= A
            g_im[t] = g_re[t] * Ai[t] + g_im[t] * Ar[t];  g_re[t] = ng;
            const float nm = m_re[t] * Ur[t] - m_im[t] * Ui[t];   // m *= U
            m_im[t] = m_re[t] * Ui[t] + m_im[t] * Ur[t];  m_re[t] = nm;
        }
    }
    __syncthreads();

    // ---- wave w (ta = w): direct b128 fragment reads, no unpack ----
    const int w    = tid >> 6;
    const int lane = tid & 63;
    const int e    = lane & 15;
    const int kg   = lane >> 4;

    f16x8 fMr[2], fMi[2], fGr[2][4], fGi[2][4];
    #pragma unroll
    for (int s = 0; s < 2; ++s) {
        const int rowm = w * 16 + e;
        const int cm   = rowm * 32 + (((4 * s + kg) ^ (rowm & 7)) << 2);
        fMr[s] = *reinterpret_cast<const f16x8*>(&s_Mr[cm]);
        fMi[s] = *reinterpret_cast<const f16x8*>(&s_Mi[cm]);
        #pragma unroll
        for (int tb = 0; tb < 4; ++tb) {
            const int rowg = tb * 16 + e;
            const int cg   = rowg * 32 + (((4 * s + kg) ^ (rowg & 7)) << 2);
            fGr[s][tb] = *reinterpret_cast<const f16x8*>(&s_Gr[cg]);
            fGi[s][tb] = *reinterpret_cast<const f16x8*>(&s_Gi[cg]);
        }
    }

    // ---- 4 tiles/wave: Re = mfma(Gr,Mr) + mfma(-Gi,Mi) ----
    #pragma unroll
    for (int tb = 0; tb < 4; ++tb) {
        f32x4 acc = {0.f, 0.f, 0.f, 0.f};
        #pragma unroll
        for (int s = 0; s < 2; ++s) {
            acc = __builtin_amdgcn_mfma_f32_16x16x32_f16(fGr[s][tb], fMr[s], acc, 0, 0, 0);
            acc = __builtin_amdgcn_mfma_f32_16x16x32_f16(fGi[s][tb], fMi[s], acc, 0, 0, 0);
        }
        // D[row=b][col=a]: b = tb*16 + kg*4 + reg, a = w*16 + e; l = 64a + b
        float4 v;
        v.x = acc[0];  v.y = acc[1];  v.z = acc[2];  v.w = acc[3];
        *reinterpret_cast<float4*>(out + h * L + (w * 16 + e) * 64
                                   + tb * 16 + kg * 4) = v;
    }
}

extern "C" void kernel_launch(void* const* d_in, const int* in_sizes, int n_in,
                              void* d_out, int out_size, void* d_ws, size_t ws_size,
                              hipStream_t stream)
{
    const float* A_abslog = (const float*)d_in[0];
    const float* A_phase  = (const float*)d_in[1];
    const float* C        = (const float*)d_in[2];
    float* out = (float*)d_out;

    sskdiag_kernel<<<H, 256, 0, stream>>>(A_abslog, A_phase, C, out);
}

// Round 14
// 9.798 us; speedup vs baseline: 1.5183x; 1.5183x over previous
//
#include <hip/hip_runtime.h>
#include <math.h>

// SSKernelDiag: out[0,h,l] = 2*Re( sum_n C'[h,n] * A[h,n]^l )
//   A  = exp(al + i*ph),  C' = (C0 + i*C1)*(A-1)/(al + i*ph)
// H=256, N=64, L=4096, CH=1.
//
// Round 14: R10 (best: 9.78us) + ONLY the fragment unpack swapped to
// v_perm_b32 (8 ops per frag-pair, R12-verified), isolating that variable.
//   l = 64a + b;  K[a,b] = sum_n M[n,a]*G[n,b], M = 2C'*U^a (U=A^64), G = A^b.
//   Re(K) = Gr^T Mr + (-Gi)^T Mi  ->  mfma_f32_16x16x32_f16.
// Grid=256 (1 head/block), 256 threads. Tables: packed {f16 re, f16 im} u32,
// row stride 76 u32.

typedef _Float16       f16x8 __attribute__((ext_vector_type(8)));
typedef unsigned int   u32x4 __attribute__((ext_vector_type(4)));
typedef float          f32x4 __attribute__((ext_vector_type(4)));

constexpr int H = 256;
constexpr int N = 64;
constexpr int L = 4096;
constexpr int STRIDE = 76;   // u32 words per table row (64 + 12 pad)

constexpr unsigned SEL_LO = 0x05040100u;  // {src1.lo16, src0.lo16}
constexpr unsigned SEL_HI = 0x07060302u;  // {src1.hi16, src0.hi16}

__global__ __launch_bounds__(256)
void sskdiag_kernel(const float* __restrict__ A_abslog,
                    const float* __restrict__ A_phase,
                    const float* __restrict__ C,
                    float* __restrict__ out)
{
    __shared__ float4   s_t1[N];            // {al, phrev, Ar, Ai}
    __shared__ float4   s_t2[N];            // {Ur, Ui, 2C'r, 2C'i}
    __shared__ __align__(16) unsigned s_G[64 * STRIDE]; // row b: {f16 Gr, f16 -Gi}
    __shared__ __align__(16) unsigned s_M[64 * STRIDE]; // row a: {f16 Mr, f16  Mi}

    const int h   = blockIdx.x;
    const int tid = threadIdx.x;

    // ---- phase A: lane n computes per-n constants (one wave) ----
    if (tid < N) {
        const int n = tid;
        const float al = A_abslog[h * N + n];
        const float ph = A_phase [h * N + n];
        const double md = (double)ph * 0.15915494309189535;   // ph/(2*pi)
        const float phrev = (float)(md - floor(md));          // frac revolutions
        const float sp = __builtin_amdgcn_sinf(phrev);        // HW trig: revs
        const float cp = __builtin_amdgcn_cosf(phrev);
        const float m  = __expf(al);
        const float Ar = m * cp, Ai = m * sp;
        const float nr = Ar - 1.0f, ni = Ai;
        const float inv = 1.0f / (al * al + ph * ph);
        const float gr = (nr * al + ni * ph) * inv;
        const float gi = (ni * al - nr * ph) * inv;
        const float cre = C[(h * N + n) * 2 + 0];
        const float cim = C[(h * N + n) * 2 + 1];
        const float Cr = 2.0f * (cre * gr - cim * gi);        // fold the *2
        const float Ci = 2.0f * (cre * gi + cim * gr);
        // U = A^64 (angle from f64 md: exact reduction)
        const double m64 = 64.0 * md;
        const float f64a = (float)(m64 - floor(m64));
        const float mg64 = __expf(64.0f * al);
        s_t1[n] = make_float4(al, phrev, Ar, Ai);
        s_t2[n] = make_float4(mg64 * __builtin_amdgcn_cosf(f64a),
                              mg64 * __builtin_amdgcn_sinf(f64a), Cr, Ci);
    }
    __syncthreads();

    // ---- table fill: thread (n, q) seeds row 16q, walks 16 rows ----
    {
        const int n = tid & 63, q = tid >> 6;
        const float4 t1 = s_t1[n];
        const float4 t2 = s_t2[n];
        const float al = t1.x, phrev = t1.y;
        const float Ar = t1.z, Ai = t1.w;
        const float Ur = t2.x, Ui = t2.y;
        // G seed: A^(16q)
        const float b0 = (float)(16 * q);
        float tg = phrev * b0;  tg -= floorf(tg);
        const float gmag = __expf(al * b0);
        float gre = gmag * __builtin_amdgcn_cosf(tg);
        float gim = gmag * __builtin_amdgcn_sinf(tg);
        // M seed: 2C' * U^(16q)   (exponent 1024q on A)
        const float a64 = (float)(1024 * q);
        float tm = phrev * a64;  tm -= floorf(tm);
        const float umag = __expf(al * a64);
        const float ure = umag * __builtin_amdgcn_cosf(tm);
        const float uim = umag * __builtin_amdgcn_sinf(tm);
        float mre = t2.z * ure - t2.w * uim;
        float mim = t2.z * uim + t2.w * ure;

        #pragma unroll
        for (int k = 0; k < 16; ++k) {
            const int row = 16 * q + k;
            union { _Float16 hh[2]; unsigned u; } pg, pm;
            pg.hh[0] = (_Float16)gre;  pg.hh[1] = (_Float16)(-gim);  // -Gi
            pm.hh[0] = (_Float16)mre;  pm.hh[1] = (_Float16)mim;
            s_G[row * STRIDE + n] = pg.u;   // lanes n: stride-1, conflict-free
            s_M[row * STRIDE + n] = pm.u;
            const float ngr = gre * Ar - gim * Ai;              // g *= A
            gim = gre * Ai + gim * Ar;  gre = ngr;
            const float nmr = mre * Ur - mim * Ui;              // m *= U
            mim = mre * Ui + mim * Ur;  mre = nmr;
        }
    }
    __syncthreads();

    // ---- fragment read (b128) + perm unpack; wave w owns ta = w ----
    const int w    = tid >> 6;
    const int lane = tid & 63;
    const int e    = lane & 15;
    const int kg   = lane >> 4;

    f16x8 fGr[2][4], fGi[2][4], fMr[2], fMi[2];

    #pragma unroll
    for (int s = 0; s < 2; ++s) {
        #pragma unroll
        for (int tb = 0; tb < 4; ++tb) {
            const unsigned* p = &s_G[(tb * 16 + e) * STRIDE + 32 * s + 8 * kg];
            const u32x4 v0 = *reinterpret_cast<const u32x4*>(p);
            const u32x4 v1 = *reinterpret_cast<const u32x4*>(p + 4);
            u32x4 rr, ii;
            rr[0] = __builtin_amdgcn_perm(v0[1], v0[0], SEL_LO);
            rr[1] = __builtin_amdgcn_perm(v0[3], v0[2], SEL_LO);
            rr[2] = __builtin_amdgcn_perm(v1[1], v1[0], SEL_LO);
            rr[3] = __builtin_amdgcn_perm(v1[3], v1[2], SEL_LO);
            ii[0] = __builtin_amdgcn_perm(v0[1], v0[0], SEL_HI);
            ii[1] = __builtin_amdgcn_perm(v0[3], v0[2], SEL_HI);
            ii[2] = __builtin_amdgcn_perm(v1[1], v1[0], SEL_HI);
            ii[3] = __builtin_amdgcn_perm(v1[3], v1[2], SEL_HI);
            fGr[s][tb] = __builtin_bit_cast(f16x8, rr);
            fGi[s][tb] = __builtin_bit_cast(f16x8, ii);
        }
        {
            const unsigned* p = &s_M[(w * 16 + e) * STRIDE + 32 * s + 8 * kg];
            const u32x4 v0 = *reinterpret_cast<const u32x4*>(p);
            const u32x4 v1 = *reinterpret_cast<const u32x4*>(p + 4);
            u32x4 rr, ii;
            rr[0] = __builtin_amdgcn_perm(v0[1], v0[0], SEL_LO);
            rr[1] = __builtin_amdgcn_perm(v0[3], v0[2], SEL_LO);
            rr[2] = __builtin_amdgcn_perm(v1[1], v1[0], SEL_LO);
            rr[3] = __builtin_amdgcn_perm(v1[3], v1[2], SEL_LO);
            ii[0] = __builtin_amdgcn_perm(v0[1], v0[0], SEL_HI);
            ii[1] = __builtin_amdgcn_perm(v0[3], v0[2], SEL_HI);
            ii[2] = __builtin_amdgcn_perm(v1[1], v1[0], SEL_HI);
            ii[3] = __builtin_amdgcn_perm(v1[3], v1[2], SEL_HI);
            fMr[s] = __builtin_bit_cast(f16x8, rr);
            fMi[s] = __builtin_bit_cast(f16x8, ii);
        }
    }

    // ---- 4 output tiles per wave: Re = mfma(Gr,Mr) + mfma(-Gi,Mi) ----
    #pragma unroll
    for (int tb = 0; tb < 4; ++tb) {
        f32x4 acc = {0.f, 0.f, 0.f, 0.f};
        #pragma unroll
        for (int s = 0; s < 2; ++s) {
            acc = __builtin_amdgcn_mfma_f32_16x16x32_f16(fGr[s][tb], fMr[s], acc, 0, 0, 0);
            acc = __builtin_amdgcn_mfma_f32_16x16x32_f16(fGi[s][tb], fMi[s], acc, 0, 0, 0);
        }
        // D[row=b][col=a]: b = tb*16 + kg*4 + reg, a = w*16 + e; l = 64a + b
        const int a = w * 16 + e;
        float4 v;
        v.x = acc[0];  v.y = acc[1];  v.z = acc[2];  v.w = acc[3];
        *reinterpret_cast<float4*>(out + h * L + a * 64 + tb * 16 + kg * 4) = v;
    }
}

extern "C" void kernel_launch(void* const* d_in, const int* in_sizes, int n_in,
                              void* d_out, int out_size, void* d_ws, size_t ws_size,
                              hipStream_t stream)
{
    const float* A_abslog = (const float*)d_in[0];
    const float* A_phase  = (const float*)d_in[1];
    const float* C        = (const float*)d_in[2];
    float* out = (float*)d_out;

    sskdiag_kernel<<<H, 256, 0, stream>>>(A_abslog, A_phase, C, out);
}